// Round 7
// baseline (126.382 us; speedup 1.0000x reference)
//
#include <hip/hip_runtime.h>
#include <math.h>

#define DIM 192
#define HW 56
#define NPIX 3136        // 56*56
#define NSAMP 16
#define GN_EPS 1e-5f

typedef float f32x2 __attribute__((ext_vector_type(2)));
typedef float f32x4 __attribute__((ext_vector_type(4)));
typedef float f32x16 __attribute__((ext_vector_type(16)));
typedef unsigned int u32x4 __attribute__((ext_vector_type(4)));
typedef _Float16 h2 __attribute__((ext_vector_type(2)));
typedef _Float16 h8 __attribute__((ext_vector_type(8)));
typedef __fp16 fp16x2 __attribute__((ext_vector_type(2)));
typedef __bf16 bf16x8 __attribute__((ext_vector_type(8)));

// ---------------- ws layout (bytes) ----------------
#define WS_OFF_PARTIALS 38535168
#define WS_OFF_STATS    38559744
#define WS_OFF_WB       38559872

__device__ __forceinline__ unsigned int pack_h2(float a, float b) {
    fp16x2 r = __builtin_amdgcn_cvt_pkrtz(a, b);
    return __builtin_bit_cast(unsigned int, r);
}

// -------- Kernel P: cast pointwise weights to bf16 --------
__global__ void conv_w_kernel(const float* __restrict__ w, __bf16* __restrict__ wb) {
    int i = blockIdx.x * 256 + threadIdx.x;
    if (i < DIM * DIM) wb[i] = (__bf16)w[i];
}

// ======== Kernel A: skew-MFMA depthwise 21x21 + 5x5 conv ========
// One wave per (n,ch) plane. Tile: 56 rows x 96 halves (f16), 48-dword stride.
// Per input row r (padded, 10..65): D[m][n] = sum_k A[m][k]*B[k][n],
//   A[m][k] = wl[m][k] (m=0..20) / wsm[m-21][k-8] (m=21..25, k=8..12)
//   B[k][n] = tile[r][2n + d' + k], d' in {0,1} -> output x = 2n + d'.
// D row m contributes to output row y = r - q, q = m (large) / m-13 (small).
// Per-lane 21-slot register ring, slot (r - q) % 21; hi half-wave uses renamed
// slots (y+4)%21 so register->slot maps are compile-time. Emit y = r-20.
// Rows r=10..19 produce junk for y<0 -> masked by QMAX guards (q <= r).
// Masked adds use fmac with {0,1} lane masks (mlo/mhi), not cndmask.
#define S2(PH, t) ((((PH) - (t)) % 21 + 21) % 21)
#define AB16(a, b) __builtin_amdgcn_alignbit((a), (b), 16)

// reg j (j=0..15): lo row m=(j&3)+8*(j>>2), hi row m=lo+4.
#define RING_Q(rg, dd, PH, QMAX) do { \
    rg[S2(PH,0)] += dd[0]; \
    rg[S2(PH,1)] += dd[1]; \
    rg[S2(PH,2)] += dd[2]; \
    rg[S2(PH,3)] += dd[3]; \
    if (12 <= (QMAX)) rg[S2(PH,8)]  += dd[4];  else rg[S2(PH,8)]  += mlo * dd[4]; \
    if (13 <= (QMAX)) rg[S2(PH,9)]  += dd[5];  else rg[S2(PH,9)]  += mlo * dd[5]; \
    if (14 <= (QMAX)) rg[S2(PH,10)] += dd[6];  else rg[S2(PH,10)] += mlo * dd[6]; \
    if (15 <= (QMAX)) rg[S2(PH,11)] += dd[7]; \
    else if (11 <= (QMAX)) rg[S2(PH,11)] += mlo * dd[7]; \
    if (20 <= (QMAX)) rg[S2(PH,16)] += dd[8]; \
    else if (16 <= (QMAX)) rg[S2(PH,16)] += mlo * dd[8]; \
    if (17 <= (QMAX)) rg[S2(PH,17)] += mlo * dd[9]; \
    rg[S2(PH,4)] += mhi * dd[9]; \
    if (18 <= (QMAX)) rg[S2(PH,18)] += mlo * dd[10]; \
    rg[S2(PH,5)] += mhi * dd[10]; \
    if (19 <= (QMAX)) rg[S2(PH,19)] += mlo * dd[11]; \
    rg[S2(PH,6)] += mhi * dd[11]; \
    if (11 <= (QMAX)) rg[S2(PH,11)] += mlo * dd[12]; \
    if (12 <= (QMAX)) rg[S2(PH,12)] += mlo * dd[13]; \
} while (0)

#define STEP(PH_, QMAX_, RVAL_) do { \
    const unsigned int* rp = base + ((RVAL_) - 10) * 48; \
    u32x4 dq = *(const u32x4*)rp; \
    unsigned int d4 = rp[4]; \
    u32x4 eq = *(const u32x4*)(rp + 8); \
    { \
        f32x16 acc = __builtin_amdgcn_mfma_f32_32x32x16_f16( \
            A0, __builtin_bit_cast(h8, dq), CZ, 0, 0, 0); \
        acc = __builtin_amdgcn_mfma_f32_32x32x16_f16( \
            A1, __builtin_bit_cast(h8, eq), acc, 0, 0, 0); \
        RING_Q(ring0, acc, PH_, QMAX_); \
    } \
    { \
        u32x4 q0, q1; \
        q0[0] = AB16(dq[1], dq[0]); q0[1] = AB16(dq[2], dq[1]); \
        q0[2] = AB16(dq[3], dq[2]); q0[3] = AB16(d4, dq[3]); \
        q1[0] = AB16(eq[1], eq[0]); q1[1] = AB16(eq[2], eq[1]); \
        q1[2] = AB16(eq[3], eq[2]); q1[3] = q1[2]; /* taps>=21: zero weights */ \
        f32x16 acc = __builtin_amdgcn_mfma_f32_32x32x16_f16( \
            A0, __builtin_bit_cast(h8, q0), CZ, 0, 0, 0); \
        acc = __builtin_amdgcn_mfma_f32_32x32x16_f16( \
            A1, __builtin_bit_cast(h8, q1), acc, 0, 0, 0); \
        RING_Q(ring1, acc, PH_, QMAX_); \
    } \
} while (0)

#define EMIT(PH_, RVAL_) do { \
    const int s0 = S2(PH_, 20), s1 = S2(PH_, 16); \
    float p0 = hi ? ring0[s1] : ring0[s0]; \
    float p1 = hi ? ring1[s1] : ring1[s0]; \
    ring0[s0] *= mhi;  /* lo lanes reset their emitted slot */ \
    ring0[s1] *= mlo;  /* hi lanes reset theirs */ \
    ring1[s0] *= mhi; \
    ring1[s1] *= mlo; \
    float t0 = p0 + __shfl_xor(p0, 32); \
    float t1 = p1 + __shfl_xor(p1, 32); \
    if (!hi && nok) { \
        const int y = (RVAL_) - 20; \
        f32x2 st; st[0] = t0; st[1] = t1; \
        *(f32x2*)(top + y * HW + 2 * n) = st; \
        lsum += t0 + t1; \
        lss += t0 * t0 + t1 * t1; \
    } \
} while (0)

__global__ __launch_bounds__(64, 2)
void dwconv_kernel(const float* __restrict__ x,
                   const float* __restrict__ wl,
                   const float* __restrict__ wsm,
                   float* __restrict__ tmp,
                   float* __restrict__ partials) {
    __shared__ unsigned int tile[56 * 48];   // 10,752 B

    const int plane = blockIdx.x;            // n*DIM + ch
    const int ch = plane % DIM;
    const int l = threadIdx.x;
    const int n = l & 31;
    const int h = l >> 5;
    const bool hi = (h == 1);
    const bool nok = (n < 28);
    const float mlo = hi ? 0.f : 1.f;
    const float mhi = hi ? 1.f : 0.f;
    const float* xp = x + (size_t)plane * NPIX;

    // zero tile (halo columns)
    {
        u32x4* t4 = (u32x4*)tile;
        for (int i = l; i < 672; i += 64) {
            u32x4 z; z[0] = 0; z[1] = 0; z[2] = 0; z[3] = 0;
            t4[i] = z;
        }
    }
    __syncthreads();
    // fill valid region: dword 5+j of row holds padded cols 10+2j, 11+2j
    for (int i = l; i < 56 * 28; i += 64) {
        int row = i / 28, j = i - row * 28;
        f32x2 v = *(const f32x2*)(xp + row * HW + 2 * j);
        tile[row * 48 + 5 + j] = pack_h2(v[0], v[1]);
    }

    // A-operands (weights): lane = weight row m (=n), element e = tap 8h+e (A0)
    // and 16+8h+e (A1); rows 21..25 carry the 5x5 weights at taps 8..12.
    h8 A0, A1;
    {
        const int m = n;
        #pragma unroll
        for (int e = 0; e < 8; ++e) {
            int tp = 8 * h + e;
            float v0 = 0.f, v1 = 0.f;
            if (m <= 20) {
                if (tp <= 20) v0 = wl[ch * 441 + m * 21 + tp];
                int tq = tp + 16;
                if (tq <= 20) v1 = wl[ch * 441 + m * 21 + tq];
            } else if (m <= 25 && tp >= 8 && tp <= 12) {
                v0 = wsm[ch * 25 + (m - 21) * 5 + (tp - 8)];
            }
            A0[e] = (_Float16)v0;
            A1[e] = (_Float16)v1;
        }
    }
    __syncthreads();

    float ring0[21], ring1[21];
    #pragma unroll
    for (int s = 0; s < 21; ++s) { ring0[s] = 0.f; ring1[s] = 0.f; }
    f32x16 CZ;
    #pragma unroll
    for (int s = 0; s < 16; ++s) CZ[s] = 0.f;

    float lsum = 0.f, lss = 0.f;
    float* top = tmp + (size_t)plane * NPIX;
    const unsigned int* base = tile + (n + 4 * h);

    // prologue: r = 10..19, mask contributions with q > r (would hit y < 0)
    #pragma unroll
    for (int rr = 0; rr < 10; ++rr) {
        STEP(10 + rr, 10 + rr, 10 + rr);
    }
    // steady state: r = 20..75 (MFMA only while r < 66); emit y = r-20 each iter
    for (int bb = 0; bb < 3; ++bb) {
        #pragma unroll
        for (int u = 0; u < 21; ++u) {
            const int r = 20 + 21 * bb + u;
            if (r > 75) continue;
            if (r < 66) {
                STEP(20 + u, 20, r);
            }
            EMIT(20 + u, r);
        }
    }

    // wave reduction (hi / n>=28 lanes contributed 0)
    #pragma unroll
    for (int off = 32; off > 0; off >>= 1) {
        lsum += __shfl_down(lsum, off);
        lss  += __shfl_down(lss, off);
    }
    if (l == 0) {
        partials[2 * plane + 0] = lsum;
        partials[2 * plane + 1] = lss;
    }
}

// -------- Kernel B: per-sample mean / rstd --------
__global__ void stats_kernel(const float* __restrict__ partials, float* __restrict__ stats) {
    const int n = blockIdx.x;
    const int t = threadIdx.x;   // 64 threads
    float s = 0.f, ss = 0.f;
    for (int c = t; c < DIM; c += 64) {
        s  += partials[2 * (n * DIM + c) + 0];
        ss += partials[2 * (n * DIM + c) + 1];
    }
    #pragma unroll
    for (int off = 32; off > 0; off >>= 1) {
        s  += __shfl_down(s, off);
        ss += __shfl_down(ss, off);
    }
    if (t == 0) {
        const float inv = 1.f / 602112.f;   // DIM*HW*HW
        float mean = s * inv;
        float var = ss * inv - mean * mean;
        stats[2 * n + 0] = mean;
        stats[2 * n + 1] = rsqrtf(var + GN_EPS);
    }
}

// fast exact-GELU via Abramowitz-Stegun 7.1.26 erf (|err| <= 1.5e-7)
__device__ __forceinline__ float fast_gelu(float y) {
    float z = fabsf(y) * 0.70710678118654752f;
    float tt = __builtin_amdgcn_rcpf(1.f + 0.3275911f * z);
    float poly = tt * (0.254829592f + tt * (-0.284496736f + tt * (1.421413741f
               + tt * (-1.453152027f + tt * 1.061405429f))));
    float er = 1.f - poly * __expf(-z * z);
    er = copysignf(er, y);
    return 0.5f * y * (1.f + er);
}

// -------- Kernel C: normalize + GELU + 1x1 conv (MFMA) + bias + residual --------
__global__ __launch_bounds__(192)
void pw_kernel(const float* __restrict__ tmp, const float* __restrict__ x,
               const float* __restrict__ gamma, const float* __restrict__ beta,
               const __bf16* __restrict__ wb, const float* __restrict__ bpw,
               const float* __restrict__ stats, float* __restrict__ out) {
    __shared__ __bf16 g_lds[32 * 200];   // [px][ci], row stride 200 bf16

    const int bid = blockIdx.x;
    const int n = bid / 98;              // 98 pixel-tiles of 32 per sample
    const int pt = bid - n * 98;
    const int px0 = pt * 32;
    const int t = threadIdx.x;           // t == ci for staging

    const float mean = stats[2 * n + 0];
    const float rstd = stats[2 * n + 1];

    {
        const float a = rstd * gamma[t];
        const float b = beta[t] - mean * a;
        const float* tp = tmp + ((size_t)n * DIM + t) * NPIX + px0;
        #pragma unroll
        for (int k = 0; k < 8; ++k) {
            f32x4 v = *(const f32x4*)(tp + 4 * k);
            #pragma unroll
            for (int j = 0; j < 4; ++j) {
                float y = v[j] * a + b;
                g_lds[(4 * k + j) * 200 + t] = (__bf16)fast_gelu(y);
            }
        }
    }
    __syncthreads();

    const int w = t >> 6;                // wave id -> co block of 64
    const int l = t & 63;
    const int lane16 = l & 15, lg = l >> 4;

    f32x4 acc[2][4];
    #pragma unroll
    for (int p = 0; p < 2; ++p)
        #pragma unroll
        for (int m = 0; m < 4; ++m) { acc[p][m][0]=0.f; acc[p][m][1]=0.f; acc[p][m][2]=0.f; acc[p][m][3]=0.f; }

    const char* gbase = (const char*)g_lds;
    #pragma unroll
    for (int kk = 0; kk < 6; ++kk) {
        const int k0 = 32 * kk;
        bf16x8 bf0 = *(const bf16x8*)(gbase + lane16 * 400 + (k0 + 8 * lg) * 2);
        bf16x8 bf1 = *(const bf16x8*)(gbase + (16 + lane16) * 400 + (k0 + 8 * lg) * 2);
        #pragma unroll
        for (int m = 0; m < 4; ++m) {
            const int co = 64 * w + 16 * m + lane16;
            bf16x8 af = *(const bf16x8*)(wb + co * DIM + k0 + 8 * lg);
            acc[0][m] = __builtin_amdgcn_mfma_f32_16x16x32_bf16(af, bf0, acc[0][m], 0, 0, 0);
            acc[1][m] = __builtin_amdgcn_mfma_f32_16x16x32_bf16(af, bf1, acc[1][m], 0, 0, 0);
        }
    }

    const float* xb = x + (size_t)n * DIM * NPIX;
    float* ob = out + (size_t)n * DIM * NPIX;
    #pragma unroll
    for (int m = 0; m < 4; ++m) {
        f32x4 b4 = *(const f32x4*)(bpw + 64 * w + 16 * m + 4 * lg);
        #pragma unroll
        for (int p = 0; p < 2; ++p)
            #pragma unroll
            for (int j = 0; j < 4; ++j) {
                const int co = 64 * w + 16 * m + 4 * lg + j;
                const int idx = co * NPIX + px0 + p * 16 + lane16;
                ob[idx] = acc[p][m][j] + b4[j] + xb[idx];
            }
    }
}

extern "C" void kernel_launch(void* const* d_in, const int* in_sizes, int n_in,
                              void* d_out, int out_size, void* d_ws, size_t ws_size,
                              hipStream_t stream) {
    (void)in_sizes; (void)n_in; (void)out_size; (void)ws_size;
    const float* x     = (const float*)d_in[0];
    const float* wl    = (const float*)d_in[1];
    const float* wsm   = (const float*)d_in[2];
    const float* gamma = (const float*)d_in[3];
    const float* beta  = (const float*)d_in[4];
    const float* wpw   = (const float*)d_in[5];
    const float* bpw   = (const float*)d_in[6];
    float* out = (float*)d_out;

    char* wsb = (char*)d_ws;
    float* tmp      = (float*)wsb;
    float* partials = (float*)(wsb + WS_OFF_PARTIALS);
    float* stats    = (float*)(wsb + WS_OFF_STATS);
    __bf16* wb      = (__bf16*)(wsb + WS_OFF_WB);

    conv_w_kernel<<<144, 256, 0, stream>>>(wpw, wb);
    dwconv_kernel<<<NSAMP * DIM, 64, 0, stream>>>(x, wl, wsm, tmp, partials);
    stats_kernel<<<NSAMP, 64, 0, stream>>>(partials, stats);
    pw_kernel<<<NSAMP * 98, 192, 0, stream>>>(tmp, x, gamma, beta, wb, bpw, stats, out);
}

// Round 10
// 114.492 us; speedup vs baseline: 1.1038x; 1.1038x over previous
//
#include <hip/hip_runtime.h>
#include <math.h>

#define DIM 192
#define HW 56
#define NPIX 3136        // 56*56
#define NSAMP 16
#define GN_EPS 1e-5f

typedef float f32x2 __attribute__((ext_vector_type(2)));
typedef float f32x4 __attribute__((ext_vector_type(4)));
typedef float f32x16 __attribute__((ext_vector_type(16)));
typedef unsigned int u32x4 __attribute__((ext_vector_type(4)));
typedef _Float16 h2 __attribute__((ext_vector_type(2)));
typedef _Float16 h8 __attribute__((ext_vector_type(8)));
typedef __bf16 bf16x8 __attribute__((ext_vector_type(8)));

// ---------------- ws layout (bytes) ----------------
#define WS_OFF_PARTIALS 38535168
#define WS_OFF_STATS    38559744
#define WS_OFF_WB       38559872

// RNE f16 pack (round-to-nearest-even)
__device__ __forceinline__ unsigned int pack_h2(float a, float b) {
    h2 h;
    h[0] = (_Float16)a;
    h[1] = (_Float16)b;
    return __builtin_bit_cast(unsigned int, h);
}

// -------- Kernel P: cast pointwise weights to bf16 --------
__global__ void conv_w_kernel(const float* __restrict__ w, __bf16* __restrict__ wb) {
    int i = blockIdx.x * 256 + threadIdx.x;
    if (i < DIM * DIM) wb[i] = (__bf16)w[i];
}

// ======== Kernel A: skew-MFMA depthwise 21x21 + 5x5 conv ========
// One wave per (n,ch) plane. Tile: 56 rows x 96 halves (f16), 48-dword stride.
// NOTE: per-lane tile pointers are DWORD-granular -> LDS reads must stay
// scalar b32 (u32x4 casts emit ds_read_b128 on 4B-aligned addrs = corrupt data;
// this was the rounds-7..9 correctness bug).
#define SL(q) ((((10 + u - (q)) % 21) + 21) % 21)

#define RING_ACC(rg, dd) do { \
    rg[SL(0)]  += dd[0]; \
    rg[SL(1)]  += dd[1]; \
    rg[SL(2)]  += dd[2]; \
    rg[SL(3)]  += dd[3]; \
    rg[SL(8)]  += dd[4]; \
    rg[SL(9)]  += dd[5]; \
    rg[SL(10)] += dd[6]; \
    rg[SL(11)] += dd[7]; \
    rg[SL(16)] += dd[8]; \
    rg[SL(17)] += hi ? 0.f : dd[9]; \
    rg[(SL(17)+13)%21] += hi ? dd[9] : 0.f; \
    rg[SL(18)] += hi ? 0.f : dd[10]; \
    rg[(SL(18)+13)%21] += hi ? dd[10] : 0.f; \
    rg[SL(19)] += hi ? 0.f : dd[11]; \
    rg[(SL(19)+13)%21] += hi ? dd[11] : 0.f; \
    rg[(SL(24)+13)%21] += hi ? 0.f : dd[12]; \
    rg[(SL(25)+13)%21] += hi ? 0.f : dd[13]; \
} while (0)

// prologue variant: only add contributions with true q <= QMAX (y >= 0)
#define RING_QG(rg, dd, QMAX) do { \
    rg[SL(0)] += dd[0]; \
    rg[SL(1)] += dd[1]; \
    rg[SL(2)] += dd[2]; \
    rg[SL(3)] += dd[3]; \
    if (12 <= (QMAX)) rg[SL(8)]  += dd[4];  else rg[SL(8)]  += hi ? 0.f : dd[4]; \
    if (13 <= (QMAX)) rg[SL(9)]  += dd[5];  else rg[SL(9)]  += hi ? 0.f : dd[5]; \
    if (14 <= (QMAX)) rg[SL(10)] += dd[6];  else rg[SL(10)] += hi ? 0.f : dd[6]; \
    if (15 <= (QMAX)) rg[SL(11)] += dd[7]; \
    else if (11 <= (QMAX)) rg[SL(11)] += hi ? 0.f : dd[7]; \
    if (20 <= (QMAX)) rg[SL(16)] += dd[8]; \
    else if (16 <= (QMAX)) rg[SL(16)] += hi ? 0.f : dd[8]; \
    if (17 <= (QMAX)) rg[SL(17)] += hi ? 0.f : dd[9]; \
    rg[(SL(17)+13)%21] += hi ? dd[9] : 0.f; \
    if (18 <= (QMAX)) rg[SL(18)] += hi ? 0.f : dd[10]; \
    rg[(SL(18)+13)%21] += hi ? dd[10] : 0.f; \
    if (19 <= (QMAX)) rg[SL(19)] += hi ? 0.f : dd[11]; \
    rg[(SL(19)+13)%21] += hi ? dd[11] : 0.f; \
    if (11 <= (QMAX)) rg[(SL(24)+13)%21] += hi ? 0.f : dd[12]; \
    if (12 <= (QMAX)) rg[(SL(25)+13)%21] += hi ? 0.f : dd[13]; \
} while (0)

#define AB16(a, b) __builtin_amdgcn_alignbit((a), (b), 16)

#define STEP(UU, QMAX_, RVAL_) do { \
    const int u = (UU); \
    const unsigned int* rp = base + ((RVAL_) - 10) * 48; \
    unsigned int d0 = rp[0], d1 = rp[1], d2 = rp[2], d3 = rp[3], d4 = rp[4]; \
    unsigned int e0 = rp[8], e1 = rp[9], e2 = rp[10], e3 = rp[11], e4 = rp[12]; \
    { \
        u32x4 q0; q0[0] = d0; q0[1] = d1; q0[2] = d2; q0[3] = d3; \
        u32x4 q1; q1[0] = e0; q1[1] = e1; q1[2] = e2; q1[3] = e3; \
        f32x16 acc = __builtin_amdgcn_mfma_f32_32x32x16_f16( \
            A0, __builtin_bit_cast(h8, q0), CZ, 0, 0, 0); \
        acc = __builtin_amdgcn_mfma_f32_32x32x16_f16( \
            A1, __builtin_bit_cast(h8, q1), acc, 0, 0, 0); \
        RING_QG(ring0, acc, QMAX_); \
    } \
    { \
        u32x4 q0, q1; \
        q0[0] = AB16(d1, d0); q0[1] = AB16(d2, d1); \
        q0[2] = AB16(d3, d2); q0[3] = AB16(d4, d3); \
        q1[0] = AB16(e1, e0); q1[1] = AB16(e2, e1); \
        q1[2] = AB16(e3, e2); q1[3] = AB16(e4, e3); \
        f32x16 acc = __builtin_amdgcn_mfma_f32_32x32x16_f16( \
            A0, __builtin_bit_cast(h8, q0), CZ, 0, 0, 0); \
        acc = __builtin_amdgcn_mfma_f32_32x32x16_f16( \
            A1, __builtin_bit_cast(h8, q1), acc, 0, 0, 0); \
        RING_QG(ring1, acc, QMAX_); \
    } \
} while (0)

#define EMIT(UU, RVAL_) do { \
    const int u = (UU); \
    const int s0 = SL(20); \
    const int s1 = SL(16); \
    float p0 = hi ? ring0[s1] : ring0[s0]; \
    float p1 = hi ? ring1[s1] : ring1[s0]; \
    ring0[s0] = hi ? ring0[s0] : 0.f; \
    ring0[s1] = hi ? 0.f : ring0[s1]; \
    ring1[s0] = hi ? ring1[s0] : 0.f; \
    ring1[s1] = hi ? 0.f : ring1[s1]; \
    float t0 = p0 + __shfl_xor(p0, 32); \
    float t1 = p1 + __shfl_xor(p1, 32); \
    if (!hi && nok) { \
        const int y = (RVAL_) - 20; \
        f32x2 st; st[0] = t0; st[1] = t1; \
        *(f32x2*)(top + y * HW + 2 * n) = st; \
        lsum += t0 + t1; \
        lss += t0 * t0 + t1 * t1; \
    } \
} while (0)

__global__ __launch_bounds__(64, 3)
void dwconv_kernel(const float* __restrict__ x,
                   const float* __restrict__ wl,
                   const float* __restrict__ wsm,
                   float* __restrict__ tmp,
                   float* __restrict__ partials) {
    __shared__ unsigned int tile[56 * 48];   // 10,752 B

    const int plane = blockIdx.x;            // n*DIM + ch
    const int ch = plane % DIM;
    const int l = threadIdx.x;
    const int n = l & 31;
    const int h = l >> 5;
    const bool hi = (h == 1);
    const bool nok = (n < 28);
    const float* xp = x + (size_t)plane * NPIX;

    // zero tile (halo columns)
    {
        u32x4* t4 = (u32x4*)tile;
        for (int i = l; i < 672; i += 64) {
            u32x4 z; z[0] = 0; z[1] = 0; z[2] = 0; z[3] = 0;
            t4[i] = z;
        }
    }
    __syncthreads();
    // fill valid region: dword 5+j of row holds padded cols 10+2j, 11+2j
    for (int i = l; i < 56 * 28; i += 64) {
        int row = i / 28, j = i - row * 28;
        f32x2 v = *(const f32x2*)(xp + row * HW + 2 * j);
        tile[row * 48 + 5 + j] = pack_h2(v[0], v[1]);
    }

    // A-operands (weights): lane = weight row m (=n), element e = tap 8h+e (A0)
    // and 16+8h+e (A1); rows 21..25 carry the 5x5 weights at taps 8..12.
    h8 A0, A1;
    {
        const int m = n;
        #pragma unroll
        for (int e = 0; e < 8; ++e) {
            int tp = 8 * h + e;
            float v0 = 0.f, v1 = 0.f;
            if (m <= 20) {
                if (tp <= 20) v0 = wl[ch * 441 + m * 21 + tp];
                int tq = tp + 16;
                if (tq <= 20) v1 = wl[ch * 441 + m * 21 + tq];
            } else if (m <= 25 && tp >= 8 && tp <= 12) {
                v0 = wsm[ch * 25 + (m - 21) * 5 + (tp - 8)];
            }
            A0[e] = (_Float16)v0;
            A1[e] = (_Float16)v1;
        }
    }
    __syncthreads();

    float ring0[21], ring1[21];
    #pragma unroll
    for (int s = 0; s < 21; ++s) { ring0[s] = 0.f; ring1[s] = 0.f; }
    f32x16 CZ;
    #pragma unroll
    for (int s = 0; s < 16; ++s) CZ[s] = 0.f;

    float lsum = 0.f, lss = 0.f;
    float* top = tmp + (size_t)plane * NPIX;
    const unsigned int* base = tile + (n + 4 * h);

    // prologue: r = 10..19, mask contributions with q > r (would hit y < 0)
    #pragma unroll
    for (int rr = 0; rr < 10; ++rr) {
        STEP(rr, 10 + rr, 10 + rr);
    }
    // steady state: r = 20..75 (MFMA only while r < 66); emit y = r-20 each iter
    for (int bb = 0; bb < 3; ++bb) {
        #pragma unroll
        for (int uu = 0; uu < 21; ++uu) {
            const int r = 20 + 21 * bb + uu;
            if (r > 75) continue;
            if (r < 66) {
                STEP(10 + uu, 20, r);
            }
            EMIT(10 + uu, r);
        }
    }

    // wave reduction (hi / n>=28 lanes contributed 0)
    #pragma unroll
    for (int off = 32; off > 0; off >>= 1) {
        lsum += __shfl_down(lsum, off);
        lss  += __shfl_down(lss, off);
    }
    if (l == 0) {
        partials[2 * plane + 0] = lsum;
        partials[2 * plane + 1] = lss;
    }
}

// -------- Kernel B: per-sample mean / rstd --------
__global__ void stats_kernel(const float* __restrict__ partials, float* __restrict__ stats) {
    const int n = blockIdx.x;
    const int t = threadIdx.x;   // 64 threads
    float s = 0.f, ss = 0.f;
    for (int c = t; c < DIM; c += 64) {
        s  += partials[2 * (n * DIM + c) + 0];
        ss += partials[2 * (n * DIM + c) + 1];
    }
    #pragma unroll
    for (int off = 32; off > 0; off >>= 1) {
        s  += __shfl_down(s, off);
        ss += __shfl_down(ss, off);
    }
    if (t == 0) {
        const float inv = 1.f / 602112.f;   // DIM*HW*HW
        float mean = s * inv;
        float var = ss * inv - mean * mean;
        stats[2 * n + 0] = mean;
        stats[2 * n + 1] = rsqrtf(var + GN_EPS);
    }
}

// fast exact-GELU via Abramowitz-Stegun 7.1.26 erf (|err| <= 1.5e-7)
__device__ __forceinline__ float fast_gelu(float y) {
    float z = fabsf(y) * 0.70710678118654752f;
    float tt = __builtin_amdgcn_rcpf(1.f + 0.3275911f * z);
    float poly = tt * (0.254829592f + tt * (-0.284496736f + tt * (1.421413741f
               + tt * (-1.453152027f + tt * 1.061405429f))));
    float er = 1.f - poly * __expf(-z * z);
    er = copysignf(er, y);
    return 0.5f * y * (1.f + er);
}

// -------- Kernel C: normalize + GELU + 1x1 conv (MFMA) + bias + residual --------
__global__ __launch_bounds__(192)
void pw_kernel(const float* __restrict__ tmp, const float* __restrict__ x,
               const float* __restrict__ gamma, const float* __restrict__ beta,
               const __bf16* __restrict__ wb, const float* __restrict__ bpw,
               const float* __restrict__ stats, float* __restrict__ out) {
    __shared__ __bf16 g_lds[32 * 200];   // [px][ci], row stride 200 bf16

    const int bid = blockIdx.x;
    const int n = bid / 98;              // 98 pixel-tiles of 32 per sample
    const int pt = bid - n * 98;
    const int px0 = pt * 32;
    const int t = threadIdx.x;           // t == ci for staging

    const float mean = stats[2 * n + 0];
    const float rstd = stats[2 * n + 1];

    {
        const float a = rstd * gamma[t];
        const float b = beta[t] - mean * a;
        const float* tp = tmp + ((size_t)n * DIM + t) * NPIX + px0;
        #pragma unroll
        for (int k = 0; k < 8; ++k) {
            f32x4 v = *(const f32x4*)(tp + 4 * k);
            #pragma unroll
            for (int j = 0; j < 4; ++j) {
                float y = v[j] * a + b;
                g_lds[(4 * k + j) * 200 + t] = (__bf16)fast_gelu(y);
            }
        }
    }
    __syncthreads();

    const int w = t >> 6;                // wave id -> co block of 64
    const int l = t & 63;
    const int lane16 = l & 15, lg = l >> 4;

    f32x4 acc[2][4];
    #pragma unroll
    for (int p = 0; p < 2; ++p)
        #pragma unroll
        for (int m = 0; m < 4; ++m) { acc[p][m][0]=0.f; acc[p][m][1]=0.f; acc[p][m][2]=0.f; acc[p][m][3]=0.f; }

    const char* gbase = (const char*)g_lds;
    #pragma unroll
    for (int kk = 0; kk < 6; ++kk) {
        const int k0 = 32 * kk;
        bf16x8 bf0 = *(const bf16x8*)(gbase + lane16 * 400 + (k0 + 8 * lg) * 2);
        bf16x8 bf1 = *(const bf16x8*)(gbase + (16 + lane16) * 400 + (k0 + 8 * lg) * 2);
        #pragma unroll
        for (int m = 0; m < 4; ++m) {
            const int co = 64 * w + 16 * m + lane16;
            bf16x8 af = *(const bf16x8*)(wb + co * DIM + k0 + 8 * lg);
            acc[0][m] = __builtin_amdgcn_mfma_f32_16x16x32_bf16(af, bf0, acc[0][m], 0, 0, 0);
            acc[1][m] = __builtin_amdgcn_mfma_f32_16x16x32_bf16(af, bf1, acc[1][m], 0, 0, 0);
        }
    }

    const float* xb = x + (size_t)n * DIM * NPIX;
    float* ob = out + (size_t)n * DIM * NPIX;
    #pragma unroll
    for (int m = 0; m < 4; ++m) {
        f32x4 b4 = *(const f32x4*)(bpw + 64 * w + 16 * m + 4 * lg);
        #pragma unroll
        for (int p = 0; p < 2; ++p)
            #pragma unroll
            for (int j = 0; j < 4; ++j) {
                const int co = 64 * w + 16 * m + 4 * lg + j;
                const int idx = co * NPIX + px0 + p * 16 + lane16;
                ob[idx] = acc[p][m][j] + b4[j] + xb[idx];
            }
    }
}

extern "C" void kernel_launch(void* const* d_in, const int* in_sizes, int n_in,
                              void* d_out, int out_size, void* d_ws, size_t ws_size,
                              hipStream_t stream) {
    (void)in_sizes; (void)n_in; (void)out_size; (void)ws_size;
    const float* x     = (const float*)d_in[0];
    const float* wl    = (const float*)d_in[1];
    const float* wsm   = (const float*)d_in[2];
    const float* gamma = (const float*)d_in[3];
    const float* beta  = (const float*)d_in[4];
    const float* wpw   = (const float*)d_in[5];
    const float* bpw   = (const float*)d_in[6];
    float* out = (float*)d_out;

    char* wsb = (char*)d_ws;
    float* tmp      = (float*)wsb;
    float* partials = (float*)(wsb + WS_OFF_PARTIALS);
    float* stats    = (float*)(wsb + WS_OFF_STATS);
    __bf16* wb      = (__bf16*)(wsb + WS_OFF_WB);

    conv_w_kernel<<<144, 256, 0, stream>>>(wpw, wb);
    dwconv_kernel<<<NSAMP * DIM, 64, 0, stream>>>(x, wl, wsm, tmp, partials);
    stats_kernel<<<NSAMP, 64, 0, stream>>>(partials, stats);
    pw_kernel<<<NSAMP * 98, 192, 0, stream>>>(tmp, x, gamma, beta, wb, bpw, stats, out);
}